// Round 4
// baseline (185.183 us; speedup 1.0000x reference)
//
#include <hip/hip_runtime.h>
#include <hip/hip_bf16.h>

// Problem constants (fixed by reference):
// B=2, N=64, L=32, C=512, H=8, head_dim=64, NL=N*L=2048
#define NLQ 2048
#define CDIM 512
#define HD 64
#define NHEADS 8

typedef __attribute__((ext_vector_type(8))) short bf16x8;
typedef __attribute__((ext_vector_type(4))) float f32x4;

#define MFMA16x16x32(A, B, Cc) __builtin_amdgcn_mfma_f32_16x16x32_bf16(A, B, Cc, 0, 0, 0)

__device__ __forceinline__ short f2bf(float x) {
    __hip_bfloat16 h = __float2bfloat16(x);
    return *reinterpret_cast<short*>(&h);
}

// XOR swizzle for a 64-row x 128-byte (64 bf16) LDS tile: breaks the 16-way
// bank conflict of stride-128B ds_read_b128 column access (T2, G4).
__device__ __forceinline__ int swz(int row, int colByte) {
    return ((row << 7) + colByte) ^ ((row & 7) << 4);
}

// ---------------------------------------------------------------------------
// Phase 1: Y = X @ W^T for 4 (X,W) pairs, output bf16 in (B,H,NL,64) layout.
// g=0: Q1 = f1·Wq1^T·alpha   g=1: K1 = f1·Wk1^T
// g=2: Q2 = f2·Wq2^T·alpha   g=3: K2 = f2·Wk2^T
// grid: g(4) x mtile(64) x ntile(8) = 2048 blocks, 256 threads (4 waves)
// ---------------------------------------------------------------------------
__global__ __launch_bounds__(256) void proj_kernel(
    const float* __restrict__ f1, const float* __restrict__ f2,
    const float* __restrict__ Wq1, const float* __restrict__ Wk1,
    const float* __restrict__ Wq2, const float* __restrict__ Wk2,
    const float* __restrict__ tau,
    __hip_bfloat16* __restrict__ qk)
{
    int bid = blockIdx.x;
    int g  = bid >> 9;          // 0..3
    int mt = (bid >> 3) & 63;   // 64 row tiles of 64 (B*NL = 4096 rows)
    int nt = bid & 7;           // 8 col tiles of 64 (C = 512)

    const float* X = (g < 2) ? f1 : f2;
    const float* W = (g == 0) ? Wq1 : (g == 1) ? Wk1 : (g == 2) ? Wq2 : Wk2;
    // scale/tau folded into Wq (positive scale commutes with everything)
    float alpha = (g == 0 || g == 2) ? (0.044194173824159216f / tau[0]) : 1.0f;
    __hip_bfloat16* Y = qk + (size_t)g * (2 * NHEADS * NLQ * HD);

    __shared__ alignas(16) short Xs[4096];   // 64 x 64 bf16, swizzled
    __shared__ alignas(16) short Wsh[4096];

    int t = threadIdx.x;
    int lane = t & 63;
    int w = t >> 6;

    f32x4 acc[4] = {};

    int m0 = mt * 64, d0 = nt * 64;

    for (int kc = 0; kc < 8; ++kc) {
        int k0 = kc * 64;
        // --- stage X and W tiles (fp32 -> bf16, swizzled) ---
        int r0 = t >> 3;
        int c0 = (t & 7) * 8;   // 8 elements per thread per row
        #pragma unroll
        for (int rr = r0; rr < 64; rr += 32) {
            const float* xs = X + (size_t)(m0 + rr) * CDIM + k0 + c0;
            float4 x0 = *(const float4*)xs;
            float4 x1 = *(const float4*)(xs + 4);
            bf16x8 xv = { f2bf(x0.x), f2bf(x0.y), f2bf(x0.z), f2bf(x0.w),
                          f2bf(x1.x), f2bf(x1.y), f2bf(x1.z), f2bf(x1.w) };
            *(bf16x8*)((char*)Xs + swz(rr, c0 * 2)) = xv;

            const float* wsrc = W + (size_t)(d0 + rr) * CDIM + k0 + c0;
            float4 w0 = *(const float4*)wsrc;
            float4 w1 = *(const float4*)(wsrc + 4);
            bf16x8 wv = { f2bf(w0.x * alpha), f2bf(w0.y * alpha),
                          f2bf(w0.z * alpha), f2bf(w0.w * alpha),
                          f2bf(w1.x * alpha), f2bf(w1.y * alpha),
                          f2bf(w1.z * alpha), f2bf(w1.w * alpha) };
            *(bf16x8*)((char*)Wsh + swz(rr, c0 * 2)) = wv;
        }
        __syncthreads();

        // --- MFMA: each wave does 16 rows x 64 cols ---
        bf16x8 af0, af1;
        {
            int rr = (w << 4) + (lane & 15);
            int cb = (lane >> 4) << 4;   // 16-byte chunk within the 128B row
            af0 = *(const bf16x8*)((const char*)Xs + swz(rr, cb));
            af1 = *(const bf16x8*)((const char*)Xs + swz(rr, cb + 64));
        }
        #pragma unroll
        for (int ns = 0; ns < 4; ++ns) {
            int rr = (ns << 4) + (lane & 15);
            int cb = (lane >> 4) << 4;
            bf16x8 b0 = *(const bf16x8*)((const char*)Wsh + swz(rr, cb));
            bf16x8 b1 = *(const bf16x8*)((const char*)Wsh + swz(rr, cb + 64));
            acc[ns] = MFMA16x16x32(af0, b0, acc[ns]);
            acc[ns] = MFMA16x16x32(af1, b1, acc[ns]);
        }
        __syncthreads();
    }

    // --- store: (row t, col d) -> qk[g][b][h][tl][hd] as bf16 ---
    #pragma unroll
    for (int ns = 0; ns < 4; ++ns) {
        #pragma unroll
        for (int j = 0; j < 4; ++j) {
            int row = m0 + (w << 4) + ((lane >> 4) << 2) + j;  // 0..4095
            int col = d0 + (ns << 4) + (lane & 15);            // 0..511
            int bb = row >> 11, tl = row & 2047;
            int hh = col >> 6, hd = col & 63;
            Y[(((size_t)(bb * NHEADS + hh)) * NLQ + tl) * HD + hd] =
                __float2bfloat16(acc[ns][j]);
        }
    }
}

// ---------------------------------------------------------------------------
// Phase 2: per (b, pair, h, qtile-of-64): stream K tiles, compute logits via
// MFMA, track per-row sum(exp(z)) and per-32-key-block max(z); epilogue
// computes exp(bm)/rowsum, pools over query-L, atomicAdd into out.
// grid: b(2) x pair(2) x h(8) x qtile(32) = 1024 blocks, 256 threads
// ---------------------------------------------------------------------------
__global__ __launch_bounds__(256) void attn_kernel(
    const __hip_bfloat16* __restrict__ qk, float* __restrict__ out)
{
    int bid = blockIdx.x;
    int qt   = bid & 31;
    int h    = (bid >> 5) & 7;
    int pair = (bid >> 8) & 1;
    int b    = bid >> 9;

    const size_t plane = (size_t)2 * NHEADS * NLQ * HD;
    const __hip_bfloat16* Qb = qk + (size_t)(pair == 0 ? 0 : 2) * plane;
    const __hip_bfloat16* Kb = qk + (size_t)(pair == 0 ? 3 : 1) * plane;
    const size_t bh = (size_t)(b * NHEADS + h) * NLQ * HD;
    const __hip_bfloat16* Q = Qb + bh;
    const __hip_bfloat16* K = Kb + bh;

    __shared__ alignas(16) short Ks[4096];   // 64 keys x 64 dim bf16, swizzled
    __shared__ float bms[64][64];            // [local q row][key block] raw logit max
    __shared__ float rowinv[64];
    __shared__ float partial[4][64];

    int t = threadIdx.x;
    int lane = t & 63;
    int w = t >> 6;

    // Q fragments (held in registers for the whole kernel)
    bf16x8 qa0, qa1;
    {
        int row = qt * 64 + (w << 4) + (lane & 15);
        const short* qp = (const short*)(Q + (size_t)row * HD) + ((lane >> 4) << 3);
        qa0 = *(const bf16x8*)qp;
        qa1 = *(const bf16x8*)(qp + 32);
    }

    float psum[4] = {0.f, 0.f, 0.f, 0.f};

    for (int kt = 0; kt < 32; ++kt) {
        int k0 = kt * 64;
        // --- stage K tile (already bf16) into swizzled LDS ---
        {
            int r0 = t >> 3;
            int c0 = (t & 7) * 8;
            #pragma unroll
            for (int rr = r0; rr < 64; rr += 32) {
                bf16x8 v = *(const bf16x8*)((const short*)(K + (size_t)(k0 + rr) * HD) + c0);
                *(bf16x8*)((char*)Ks + swz(rr, c0 * 2)) = v;
            }
        }
        __syncthreads();

        f32x4 acc[4] = {};
        #pragma unroll
        for (int ks = 0; ks < 4; ++ks) {
            int rr = (ks << 4) + (lane & 15);
            int cb = (lane >> 4) << 4;
            bf16x8 b0 = *(const bf16x8*)((const char*)Ks + swz(rr, cb));
            bf16x8 b1 = *(const bf16x8*)((const char*)Ks + swz(rr, cb + 64));
            acc[ks] = MFMA16x16x32(qa0, b0, acc[ks]);
            acc[ks] = MFMA16x16x32(qa1, b1, acc[ks]);
        }
        __syncthreads();   // all waves done reading Ks before next stage

        // --- per-element: exp-sum + per-32-key block max ---
        #pragma unroll
        for (int j = 0; j < 4; ++j) {
            float v0 = acc[0][j], v1 = acc[1][j], v2 = acc[2][j], v3 = acc[3][j];
            psum[j] += __expf(v0) + __expf(v1) + __expf(v2) + __expf(v3);
            float bm0 = fmaxf(v0, v1);   // keys k0..k0+31 (cols in ks 0,1)
            float bm1 = fmaxf(v2, v3);   // keys k0+32..k0+63
            #pragma unroll
            for (int m = 1; m < 16; m <<= 1) {
                bm0 = fmaxf(bm0, __shfl_xor(bm0, m));
                bm1 = fmaxf(bm1, __shfl_xor(bm1, m));
            }
            if ((lane & 15) == 0) {
                int row = (w << 4) + ((lane >> 4) << 2) + j;
                bms[row][2 * kt]     = bm0;
                bms[row][2 * kt + 1] = bm1;
            }
        }
    }

    // --- row sums (reduce per-lane partials across the 16-lane key groups) ---
    #pragma unroll
    for (int j = 0; j < 4; ++j) {
        float s = psum[j];
        #pragma unroll
        for (int m = 1; m < 16; m <<= 1) s += __shfl_xor(s, m);
        if ((lane & 15) == 0) {
            int row = (w << 4) + ((lane >> 4) << 2) + j;
            rowinv[row] = 1.0f / s;
        }
    }
    __syncthreads();

    // --- epilogue: pool exp(bm)*rowinv over the 64 local q rows ---
    {
        int n2 = t & 63;
        int rg = t >> 6;    // 4 groups of 16 rows
        float a = 0.f;
        #pragma unroll
        for (int r = rg * 16; r < rg * 16 + 16; ++r)
            a += __expf(bms[r][n2]) * rowinv[r];
        partial[rg][n2] = a;
    }
    __syncthreads();

    if (t < 128) {
        int n1l = t >> 6, n2 = t & 63;
        float val = (partial[2 * n1l][n2] + partial[2 * n1l + 1][n2]) * (1.0f / 512.0f);
        int n1 = qt * 2 + n1l;
        atomicAdd(&out[((size_t)b * 64 + n1) * 64 + n2], val);
    }
}

extern "C" void kernel_launch(void* const* d_in, const int* in_sizes, int n_in,
                              void* d_out, int out_size, void* d_ws, size_t ws_size,
                              hipStream_t stream) {
    const float* f1  = (const float*)d_in[0];
    const float* f2  = (const float*)d_in[1];
    const float* Wq1 = (const float*)d_in[2];
    const float* Wk1 = (const float*)d_in[3];
    const float* Wq2 = (const float*)d_in[4];
    const float* Wk2 = (const float*)d_in[5];
    const float* tau = (const float*)d_in[6];
    float* out = (float*)d_out;
    __hip_bfloat16* qk = (__hip_bfloat16*)d_ws;   // 4 x (2*8*2048*64) bf16 = 16 MB

    hipMemsetAsync(d_out, 0, (size_t)out_size * sizeof(float), stream);
    proj_kernel<<<dim3(2048), dim3(256), 0, stream>>>(f1, f2, Wq1, Wk1, Wq2, Wk2, tau, qk);
    attn_kernel<<<dim3(1024), dim3(256), 0, stream>>>(qk, out);
}

// Round 5
// 144.049 us; speedup vs baseline: 1.2856x; 1.2856x over previous
//
#include <hip/hip_runtime.h>
#include <hip/hip_bf16.h>

// B=2, N=64, L=32, C=512, H=8, head_dim=64, NL=2048
#define NLQ 2048
#define CDIM 512
#define HD 64
#define NHEADS 8

typedef __attribute__((ext_vector_type(8))) short bf16x8;
typedef __attribute__((ext_vector_type(4))) float f32x4;

#define MFMA(A, B, Cc) __builtin_amdgcn_mfma_f32_16x16x32_bf16(A, B, Cc, 0, 0, 0)

__device__ __forceinline__ short f2bf(float x) {
    __hip_bfloat16 h = __float2bfloat16(x);
    return *reinterpret_cast<short*>(&h);
}

// XOR swizzle for 64-row x 128-byte LDS tiles (T2/G4): kills the 16-way bank
// conflict of stride-128B ds_read_b128 column access.
__device__ __forceinline__ int swz(int row, int colByte) {
    return ((row << 7) + colByte) ^ ((row & 7) << 4);
}

// ws layout (bf16 elements):
//   [0)        qk    : 4 planes x 2,097,152 (Q1,K1,Q2,K2 in (b,h,tl,hd))
//   [8388608)  Xb1   : 2,097,152  (f1 as bf16, 4096x512)
//   [10485760) Xb2   : 2,097,152
//   [12582912) Wb    : 4 x 262,144 (Wq1*alpha, Wk1, Wq2*alpha, Wk2)
#define QK_ELEMS   8388608
#define X_ELEMS    2097152
#define W_ELEMS    262144
#define PLANE      2097152

// ---------------------------------------------------------------------------
// Pass 0: fp32 -> bf16 conversion. alpha = (C^-0.5 / tau) * log2(e) folded
// into Wq1/Wq2 so attention logits arrive in log2-domain (exp2 downstream).
// grid: 2560 blocks x 256 (blocks 0-1023: f1, 1024-2047: f2, then 4x128: W)
// ---------------------------------------------------------------------------
__global__ __launch_bounds__(256) void convert_kernel(
    const float* __restrict__ f1, const float* __restrict__ f2,
    const float* __restrict__ Wq1, const float* __restrict__ Wk1,
    const float* __restrict__ Wq2, const float* __restrict__ Wk2,
    const float* __restrict__ tau, short* __restrict__ ws)
{
    short* Xb1 = ws + QK_ELEMS;
    short* Xb2 = Xb1 + X_ELEMS;
    short* Wb  = Xb2 + X_ELEMS;
    float la = 0.044194173824159216f * 1.4426950408889634f / tau[0];

    int bid = blockIdx.x;
    const float* src; short* dst; float a = 1.0f; int idx;
    if (bid < 1024)       { src = f1; dst = Xb1; idx = bid; }
    else if (bid < 2048)  { src = f2; dst = Xb2; idx = bid - 1024; }
    else {
        int wseg = (bid - 2048) >> 7;       // 0..3
        idx = (bid - 2048) & 127;
        src = (wseg == 0) ? Wq1 : (wseg == 1) ? Wk1 : (wseg == 2) ? Wq2 : Wk2;
        dst = Wb + wseg * W_ELEMS;
        a = (wseg == 0 || wseg == 2) ? la : 1.0f;
    }
    int off = idx * 2048 + threadIdx.x * 8;
    float4 x0 = *(const float4*)(src + off);
    float4 x1 = *(const float4*)(src + off + 4);
    bf16x8 v = { f2bf(x0.x * a), f2bf(x0.y * a), f2bf(x0.z * a), f2bf(x0.w * a),
                 f2bf(x1.x * a), f2bf(x1.y * a), f2bf(x1.z * a), f2bf(x1.w * a) };
    *(bf16x8*)(dst + off) = v;
}

// ---------------------------------------------------------------------------
// Pass 1: Y = X @ W^T, all-bf16, double-buffered LDS (1 barrier/iter).
// grid: g(4) x mt(64) x nt(8) = 2048 blocks, 256 threads (4 waves)
// ---------------------------------------------------------------------------
__global__ __launch_bounds__(256) void proj_kernel(short* __restrict__ ws)
{
    const short* Xb1 = ws + QK_ELEMS;
    const short* Xb2 = Xb1 + X_ELEMS;
    const short* Wb  = Xb2 + X_ELEMS;
    short* qk = ws;

    int bid = blockIdx.x;
    int g  = bid >> 9;
    int mt = (bid >> 3) & 63;
    int nt = bid & 7;

    const short* X = (g < 2) ? Xb1 : Xb2;
    const short* W = Wb + g * W_ELEMS;
    short* Y = qk + g * PLANE;

    __shared__ alignas(16) short Xs[2][4096];
    __shared__ alignas(16) short Wsh[2][4096];

    int t = threadIdx.x;
    int lane = t & 63;
    int w = t >> 6;
    int m0 = mt * 64, d0 = nt * 64;

    f32x4 acc[4] = {};

    int srow = t >> 2;            // 0..63
    int sc   = (t & 3) * 16;      // elem col 0/16/32/48
    const short* xbase = X + (m0 + srow) * CDIM + sc;
    const short* wbase = W + (d0 + srow) * CDIM + sc;

    // prologue: stage kc=0 into buffer 0
    bf16x8 xa = *(const bf16x8*)(xbase);
    bf16x8 xb = *(const bf16x8*)(xbase + 8);
    bf16x8 wa = *(const bf16x8*)(wbase);
    bf16x8 wb = *(const bf16x8*)(wbase + 8);
    *(bf16x8*)((char*)Xs[0]  + swz(srow, sc * 2))      = xa;
    *(bf16x8*)((char*)Xs[0]  + swz(srow, sc * 2 + 16)) = xb;
    *(bf16x8*)((char*)Wsh[0] + swz(srow, sc * 2))      = wa;
    *(bf16x8*)((char*)Wsh[0] + swz(srow, sc * 2 + 16)) = wb;
    __syncthreads();

    for (int kc = 0; kc < 8; ++kc) {
        int cur = kc & 1;
        if (kc < 7) {   // issue next-tile loads early (T14)
            const short* xn = xbase + (kc + 1) * 64;
            const short* wn = wbase + (kc + 1) * 64;
            xa = *(const bf16x8*)(xn); xb = *(const bf16x8*)(xn + 8);
            wa = *(const bf16x8*)(wn); wb = *(const bf16x8*)(wn + 8);
        }
        bf16x8 af0, af1;
        {
            int rr = (w << 4) + (lane & 15);
            int cb = (lane >> 4) << 4;
            af0 = *(const bf16x8*)((const char*)Xs[cur] + swz(rr, cb));
            af1 = *(const bf16x8*)((const char*)Xs[cur] + swz(rr, cb + 64));
        }
        #pragma unroll
        for (int ns = 0; ns < 4; ++ns) {
            int rr = (ns << 4) + (lane & 15);
            int cb = (lane >> 4) << 4;
            bf16x8 b0 = *(const bf16x8*)((const char*)Wsh[cur] + swz(rr, cb));
            bf16x8 b1 = *(const bf16x8*)((const char*)Wsh[cur] + swz(rr, cb + 64));
            acc[ns] = MFMA(af0, b0, acc[ns]);
            acc[ns] = MFMA(af1, b1, acc[ns]);
        }
        if (kc < 7) {
            int nx = cur ^ 1;
            *(bf16x8*)((char*)Xs[nx]  + swz(srow, sc * 2))      = xa;
            *(bf16x8*)((char*)Xs[nx]  + swz(srow, sc * 2 + 16)) = xb;
            *(bf16x8*)((char*)Wsh[nx] + swz(srow, sc * 2))      = wa;
            *(bf16x8*)((char*)Wsh[nx] + swz(srow, sc * 2 + 16)) = wb;
        }
        __syncthreads();
    }

    // store: (row, col d) -> qk[g][b][h][tl][hd]  (layout verified round 4)
    #pragma unroll
    for (int ns = 0; ns < 4; ++ns) {
        #pragma unroll
        for (int j = 0; j < 4; ++j) {
            int row = m0 + (w << 4) + ((lane >> 4) << 2) + j;
            int col = d0 + (ns << 4) + (lane & 15);
            int bb = row >> 11, tl = row & 2047;
            int hh = col >> 6, hd = col & 63;
            Y[((bb * NHEADS + hh) * NLQ + tl) * HD + hd] = f2bf(acc[ns][j]);
        }
    }
}

// ---------------------------------------------------------------------------
// Pass 2: swapped-operand QK^T (D[key][q]), log2-domain logits, exp2 softmax
// with block-max pooling. Double-buffered K staging, 1 barrier/iter.
// grid: b(2) x pair(2) x h(8) x qt(32) = 1024 blocks, 256 threads
// ---------------------------------------------------------------------------
__global__ __launch_bounds__(256) void attn_kernel(
    const short* __restrict__ qk, float* __restrict__ out)
{
    int bid = blockIdx.x;
    int qt   = bid & 31;
    int h    = (bid >> 5) & 7;
    int pair = (bid >> 8) & 1;
    int b    = bid >> 9;

    const short* Qp = qk + (pair ? 2 : 0) * PLANE;   // Q1 or Q2 (alpha folded)
    const short* Kp = qk + (pair ? 1 : 3) * PLANE;   // K2 or K1
    const int bh = (b * NHEADS + h) * NLQ * HD;
    const short* Q = Qp + bh;
    const short* K = Kp + bh;

    __shared__ alignas(16) short Ks[2][4096];   // 2 x (64 keys x 64 d)
    __shared__ float bms[64][65];               // [key-block][q row], padded
    __shared__ float rowinv[64];
    __shared__ float partial[4][64];

    int t = threadIdx.x;
    int lane = t & 63;
    int w = t >> 6;

    // Q as B-operand: col = q = lane&15 (+w*16), k-chunk = lane>>4
    bf16x8 qb0, qb1;
    {
        int row = qt * 64 + (w << 4) + (lane & 15);
        const short* qp = Q + row * HD + ((lane >> 4) << 3);
        qb0 = *(const bf16x8*)qp;
        qb1 = *(const bf16x8*)(qp + 32);
    }

    int srow = t >> 2;
    int sc   = (t & 3) * 16;
    const short* kbase = K + srow * HD + sc;

    float psum = 0.f;

    // prologue: stage key-tile 0
    bf16x8 ka = *(const bf16x8*)(kbase);
    bf16x8 kb = *(const bf16x8*)(kbase + 8);
    *(bf16x8*)((char*)Ks[0] + swz(srow, sc * 2))      = ka;
    *(bf16x8*)((char*)Ks[0] + swz(srow, sc * 2 + 16)) = kb;
    __syncthreads();

    for (int kt = 0; kt < 32; ++kt) {
        int cur = kt & 1;
        if (kt < 31) {   // issue next-tile loads early; land after compute
            const short* kn = kbase + (kt + 1) * 64 * HD;
            ka = *(const bf16x8*)(kn);
            kb = *(const bf16x8*)(kn + 8);
        }

        f32x4 acc[4] = {};
        #pragma unroll
        for (int ks = 0; ks < 4; ++ks) {
            int rr = (ks << 4) + (lane & 15);
            int cb = (lane >> 4) << 4;
            bf16x8 a0 = *(const bf16x8*)((const char*)Ks[cur] + swz(rr, cb));
            bf16x8 a1 = *(const bf16x8*)((const char*)Ks[cur] + swz(rr, cb + 64));
            acc[ks] = MFMA(a0, qb0, acc[ks]);   // D[key][q]
            acc[ks] = MFMA(a1, qb1, acc[ks]);
        }

        // lane holds 16 logits (4 ks x 4 j) for q = w*16 + (lane&15),
        // key = ks*16 + (lane>>4)*4 + j  -> block0 = ks{0,1}, block1 = ks{2,3}
        float bm0 = -1e30f, bm1 = -1e30f;
        #pragma unroll
        for (int ks = 0; ks < 4; ++ks) {
            #pragma unroll
            for (int j = 0; j < 4; ++j) {
                float v = acc[ks][j];
                psum += exp2f(v);
                if (ks < 2) bm0 = fmaxf(bm0, v); else bm1 = fmaxf(bm1, v);
            }
        }
        bm0 = fmaxf(bm0, __shfl_xor(bm0, 16));
        bm0 = fmaxf(bm0, __shfl_xor(bm0, 32));
        bm1 = fmaxf(bm1, __shfl_xor(bm1, 16));
        bm1 = fmaxf(bm1, __shfl_xor(bm1, 32));
        if (lane < 16) {
            bms[2 * kt][(w << 4) + lane]     = bm0;
            bms[2 * kt + 1][(w << 4) + lane] = bm1;
        }

        if (kt < 31) {
            int nx = cur ^ 1;
            *(bf16x8*)((char*)Ks[nx] + swz(srow, sc * 2))      = ka;
            *(bf16x8*)((char*)Ks[nx] + swz(srow, sc * 2 + 16)) = kb;
        }
        __syncthreads();
    }

    // full row sums (reduce the per-lane key-slices)
    psum += __shfl_xor(psum, 16);
    psum += __shfl_xor(psum, 32);
    if (lane < 16) rowinv[(w << 4) + lane] = 1.0f / psum;
    __syncthreads();

    // pool exp2(blockmax)/rowsum over the 64 local q rows
    {
        int n2 = t & 63;
        int rg = t >> 6;
        float a = 0.f;
        #pragma unroll
        for (int r = rg * 16; r < rg * 16 + 16; ++r)
            a += exp2f(bms[n2][r]) * rowinv[r];
        partial[rg][n2] = a;
    }
    __syncthreads();

    if (t < 128) {
        int n1l = t >> 6, n2 = t & 63;
        float val = (partial[2 * n1l][n2] + partial[2 * n1l + 1][n2]) * (1.0f / 512.0f);
        int n1 = qt * 2 + n1l;
        atomicAdd(&out[(b * 64 + n1) * 64 + n2], val);
    }
}

extern "C" void kernel_launch(void* const* d_in, const int* in_sizes, int n_in,
                              void* d_out, int out_size, void* d_ws, size_t ws_size,
                              hipStream_t stream) {
    const float* f1  = (const float*)d_in[0];
    const float* f2  = (const float*)d_in[1];
    const float* Wq1 = (const float*)d_in[2];
    const float* Wk1 = (const float*)d_in[3];
    const float* Wq2 = (const float*)d_in[4];
    const float* Wk2 = (const float*)d_in[5];
    const float* tau = (const float*)d_in[6];
    float* out = (float*)d_out;
    short* ws = (short*)d_ws;    // ~26 MiB bf16 scratch

    hipMemsetAsync(d_out, 0, (size_t)out_size * sizeof(float), stream);
    convert_kernel<<<dim3(2560), dim3(256), 0, stream>>>(f1, f2, Wq1, Wk1, Wq2, Wk2, tau, ws);
    proj_kernel<<<dim3(2048), dim3(256), 0, stream>>>(ws);
    attn_kernel<<<dim3(1024), dim3(256), 0, stream>>>(ws, out);
}

// Round 6
// 132.726 us; speedup vs baseline: 1.3952x; 1.0853x over previous
//
#include <hip/hip_runtime.h>
#include <hip/hip_bf16.h>

// B=2, N=64, L=32, C=512, H=8, head_dim=64, NL=2048
#define NLQ 2048
#define CDIM 512
#define HD 64
#define NHEADS 8

typedef __attribute__((ext_vector_type(8))) short bf16x8;
typedef __attribute__((ext_vector_type(4))) float f32x4;

#define MFMA(A, B, Cc) __builtin_amdgcn_mfma_f32_16x16x32_bf16(A, B, Cc, 0, 0, 0)

__device__ __forceinline__ short f2bf(float x) {
    __hip_bfloat16 h = __float2bfloat16(x);
    return *reinterpret_cast<short*>(&h);
}

// Single-instruction 2^x (trans pipe). exp2f() is ocml with denorm fixup
// (~6-8 instrs); logits are pre-scaled by log2(e) so raw v_exp_f32 is exact.
__device__ __forceinline__ float fast_exp2(float x) {
    float r;
    asm("v_exp_f32 %0, %1" : "=v"(r) : "v"(x));
    return r;
}

// XOR swizzle for 64-row x 128-byte LDS tiles (T2/G4).
__device__ __forceinline__ int swz(int row, int colByte) {
    return ((row << 7) + colByte) ^ ((row & 7) << 4);
}

// ws layout (bf16 elements)
#define QK_ELEMS   8388608
#define X_ELEMS    2097152
#define W_ELEMS    262144
#define PLANE      2097152

// ---------------------------------------------------------------------------
// Pass 0: fp32 -> bf16. alpha = (C^-0.5 / tau) * log2(e) folded into Wq.
// ---------------------------------------------------------------------------
__global__ __launch_bounds__(256) void convert_kernel(
    const float* __restrict__ f1, const float* __restrict__ f2,
    const float* __restrict__ Wq1, const float* __restrict__ Wk1,
    const float* __restrict__ Wq2, const float* __restrict__ Wk2,
    const float* __restrict__ tau, short* __restrict__ ws)
{
    short* Xb1 = ws + QK_ELEMS;
    short* Xb2 = Xb1 + X_ELEMS;
    short* Wb  = Xb2 + X_ELEMS;
    float la = 0.044194173824159216f * 1.4426950408889634f / tau[0];

    int bid = blockIdx.x;
    const float* src; short* dst; float a = 1.0f; int idx;
    if (bid < 1024)       { src = f1; dst = Xb1; idx = bid; }
    else if (bid < 2048)  { src = f2; dst = Xb2; idx = bid - 1024; }
    else {
        int wseg = (bid - 2048) >> 7;
        idx = (bid - 2048) & 127;
        src = (wseg == 0) ? Wq1 : (wseg == 1) ? Wk1 : (wseg == 2) ? Wq2 : Wk2;
        dst = Wb + wseg * W_ELEMS;
        a = (wseg == 0 || wseg == 2) ? la : 1.0f;
    }
    int off = idx * 2048 + threadIdx.x * 8;
    float4 x0 = *(const float4*)(src + off);
    float4 x1 = *(const float4*)(src + off + 4);
    bf16x8 v = { f2bf(x0.x * a), f2bf(x0.y * a), f2bf(x0.z * a), f2bf(x0.w * a),
                 f2bf(x1.x * a), f2bf(x1.y * a), f2bf(x1.z * a), f2bf(x1.w * a) };
    *(bf16x8*)(dst + off) = v;
}

// ---------------------------------------------------------------------------
// Pass 1: Y = X @ W^T, bf16, double-buffered. Operands SWAPPED (A=W, B=X) so
// D[row=d][col=m]: j indexes 4 consecutive hd -> one 8B packed store per ns
// (4 stores/thread instead of 16 scalar 2B stores).
// grid: g(4) x mt(64) x nt(8) = 2048 blocks, 256 threads
// ---------------------------------------------------------------------------
__global__ __launch_bounds__(256) void proj_kernel(short* __restrict__ ws)
{
    const short* Xb1 = ws + QK_ELEMS;
    const short* Xb2 = Xb1 + X_ELEMS;
    const short* Wb  = Xb2 + X_ELEMS;
    short* qk = ws;

    int bid = blockIdx.x;
    int g  = bid >> 9;
    int mt = (bid >> 3) & 63;
    int nt = bid & 7;

    const short* X = (g < 2) ? Xb1 : Xb2;
    const short* W = Wb + g * W_ELEMS;
    short* Y = qk + g * PLANE;

    __shared__ alignas(16) short Xs[2][4096];
    __shared__ alignas(16) short Wsh[2][4096];

    int t = threadIdx.x;
    int lane = t & 63;
    int w = t >> 6;
    int m0 = mt * 64, d0 = nt * 64;

    f32x4 acc[4] = {};

    int srow = t >> 2;
    int sc   = (t & 3) * 16;
    const short* xbase = X + (m0 + srow) * CDIM + sc;
    const short* wbase = W + (d0 + srow) * CDIM + sc;

    bf16x8 xa = *(const bf16x8*)(xbase);
    bf16x8 xb = *(const bf16x8*)(xbase + 8);
    bf16x8 wa = *(const bf16x8*)(wbase);
    bf16x8 wb = *(const bf16x8*)(wbase + 8);
    *(bf16x8*)((char*)Xs[0]  + swz(srow, sc * 2))      = xa;
    *(bf16x8*)((char*)Xs[0]  + swz(srow, sc * 2 + 16)) = xb;
    *(bf16x8*)((char*)Wsh[0] + swz(srow, sc * 2))      = wa;
    *(bf16x8*)((char*)Wsh[0] + swz(srow, sc * 2 + 16)) = wb;
    __syncthreads();

    for (int kc = 0; kc < 8; ++kc) {
        int cur = kc & 1;
        if (kc < 7) {
            const short* xn = xbase + (kc + 1) * 64;
            const short* wn = wbase + (kc + 1) * 64;
            xa = *(const bf16x8*)(xn); xb = *(const bf16x8*)(xn + 8);
            wa = *(const bf16x8*)(wn); wb = *(const bf16x8*)(wn + 8);
        }
        // B-operand: X rows (this wave's 16 m values)
        bf16x8 bf0, bf1;
        {
            int rr = (w << 4) + (lane & 15);
            int cb = (lane >> 4) << 4;
            bf0 = *(const bf16x8*)((const char*)Xs[cur] + swz(rr, cb));
            bf1 = *(const bf16x8*)((const char*)Xs[cur] + swz(rr, cb + 64));
        }
        #pragma unroll
        for (int ns = 0; ns < 4; ++ns) {
            int rr = (ns << 4) + (lane & 15);
            int cb = (lane >> 4) << 4;
            bf16x8 a0 = *(const bf16x8*)((const char*)Wsh[cur] + swz(rr, cb));
            bf16x8 a1 = *(const bf16x8*)((const char*)Wsh[cur] + swz(rr, cb + 64));
            acc[ns] = MFMA(a0, bf0, acc[ns]);   // D[d][m]
            acc[ns] = MFMA(a1, bf1, acc[ns]);
        }
        if (kc < 7) {
            int nx = cur ^ 1;
            *(bf16x8*)((char*)Xs[nx]  + swz(srow, sc * 2))      = xa;
            *(bf16x8*)((char*)Xs[nx]  + swz(srow, sc * 2 + 16)) = xb;
            *(bf16x8*)((char*)Wsh[nx] + swz(srow, sc * 2))      = wa;
            *(bf16x8*)((char*)Wsh[nx] + swz(srow, sc * 2 + 16)) = wb;
        }
        __syncthreads();
    }

    // store: m = col = lane&15 (+w*16); d = ns*16 + (lane>>4)*4 + j
    {
        int m = m0 + (w << 4) + (lane & 15);
        int bb = m >> 11, tl = m & 2047;
        short* yrow = Y + ((bb * NHEADS + nt) * NLQ + tl) * HD + ((lane >> 4) << 2);
        #pragma unroll
        for (int ns = 0; ns < 4; ++ns) {
            short4 v = { f2bf(acc[ns][0]), f2bf(acc[ns][1]),
                         f2bf(acc[ns][2]), f2bf(acc[ns][3]) };
            *(short4*)(yrow + (ns << 4)) = v;
        }
    }
}

// ---------------------------------------------------------------------------
// Pass 2: swapped-operand QK^T (D[key][q]), log2-domain logits, raw v_exp_f32.
// grid: b(2) x pair(2) x h(8) x qt(32) = 1024 blocks, 256 threads
// ---------------------------------------------------------------------------
__global__ __launch_bounds__(256) void attn_kernel(
    const short* __restrict__ qk, float* __restrict__ out)
{
    int bid = blockIdx.x;
    int qt   = bid & 31;
    int h    = (bid >> 5) & 7;
    int pair = (bid >> 8) & 1;
    int b    = bid >> 9;

    const short* Qp = qk + (pair ? 2 : 0) * PLANE;
    const short* Kp = qk + (pair ? 1 : 3) * PLANE;
    const int bh = (b * NHEADS + h) * NLQ * HD;
    const short* Q = Qp + bh;
    const short* K = Kp + bh;

    __shared__ alignas(16) short Ks[2][4096];
    __shared__ float bms[64][65];
    __shared__ float rowinv[64];
    __shared__ float partial[4][64];

    int t = threadIdx.x;
    int lane = t & 63;
    int w = t >> 6;

    bf16x8 qb0, qb1;
    {
        int row = qt * 64 + (w << 4) + (lane & 15);
        const short* qp = Q + row * HD + ((lane >> 4) << 3);
        qb0 = *(const bf16x8*)qp;
        qb1 = *(const bf16x8*)(qp + 32);
    }

    int srow = t >> 2;
    int sc   = (t & 3) * 16;
    const short* kbase = K + srow * HD + sc;

    float ps0 = 0.f, ps1 = 0.f, ps2 = 0.f, ps3 = 0.f;   // ILP accumulators

    bf16x8 ka = *(const bf16x8*)(kbase);
    bf16x8 kb = *(const bf16x8*)(kbase + 8);
    *(bf16x8*)((char*)Ks[0] + swz(srow, sc * 2))      = ka;
    *(bf16x8*)((char*)Ks[0] + swz(srow, sc * 2 + 16)) = kb;
    __syncthreads();

    for (int kt = 0; kt < 32; ++kt) {
        int cur = kt & 1;
        if (kt < 31) {
            const short* kn = kbase + (kt + 1) * 64 * HD;
            ka = *(const bf16x8*)(kn);
            kb = *(const bf16x8*)(kn + 8);
        }

        f32x4 acc[4] = {};
        #pragma unroll
        for (int ks = 0; ks < 4; ++ks) {
            int rr = (ks << 4) + (lane & 15);
            int cb = (lane >> 4) << 4;
            bf16x8 a0 = *(const bf16x8*)((const char*)Ks[cur] + swz(rr, cb));
            bf16x8 a1 = *(const bf16x8*)((const char*)Ks[cur] + swz(rr, cb + 64));
            acc[ks] = MFMA(a0, qb0, acc[ks]);   // D[key][q]
            acc[ks] = MFMA(a1, qb1, acc[ks]);
        }

        // exp-sums (4 independent chains) — raw v_exp_f32
        ps0 += fast_exp2(acc[0][0]) + fast_exp2(acc[0][1])
             + fast_exp2(acc[0][2]) + fast_exp2(acc[0][3]);
        ps1 += fast_exp2(acc[1][0]) + fast_exp2(acc[1][1])
             + fast_exp2(acc[1][2]) + fast_exp2(acc[1][3]);
        ps2 += fast_exp2(acc[2][0]) + fast_exp2(acc[2][1])
             + fast_exp2(acc[2][2]) + fast_exp2(acc[2][3]);
        ps3 += fast_exp2(acc[3][0]) + fast_exp2(acc[3][1])
             + fast_exp2(acc[3][2]) + fast_exp2(acc[3][3]);

        // block maxima: 8 values each, max3-friendly nesting (v_max3_f32)
        float t0 = fmaxf(fmaxf(acc[0][0], acc[0][1]), acc[0][2]);
        float t1 = fmaxf(fmaxf(acc[0][3], acc[1][0]), acc[1][1]);
        float bm0 = fmaxf(fmaxf(t0, t1), fmaxf(acc[1][2], acc[1][3]));
        float t2 = fmaxf(fmaxf(acc[2][0], acc[2][1]), acc[2][2]);
        float t3 = fmaxf(fmaxf(acc[2][3], acc[3][0]), acc[3][1]);
        float bm1 = fmaxf(fmaxf(t2, t3), fmaxf(acc[3][2], acc[3][3]));

        bm0 = fmaxf(bm0, __shfl_xor(bm0, 16));
        bm0 = fmaxf(bm0, __shfl_xor(bm0, 32));
        bm1 = fmaxf(bm1, __shfl_xor(bm1, 16));
        bm1 = fmaxf(bm1, __shfl_xor(bm1, 32));
        if (lane < 16) {
            bms[2 * kt][(w << 4) + lane]     = bm0;
            bms[2 * kt + 1][(w << 4) + lane] = bm1;
        }

        if (kt < 31) {
            int nx = cur ^ 1;
            *(bf16x8*)((char*)Ks[nx] + swz(srow, sc * 2))      = ka;
            *(bf16x8*)((char*)Ks[nx] + swz(srow, sc * 2 + 16)) = kb;
        }
        __syncthreads();
    }

    float psum = (ps0 + ps1) + (ps2 + ps3);
    psum += __shfl_xor(psum, 16);
    psum += __shfl_xor(psum, 32);
    if (lane < 16) rowinv[(w << 4) + lane] = 1.0f / psum;
    __syncthreads();

    {
        int n2 = t & 63;
        int rg = t >> 6;
        float a = 0.f;
        #pragma unroll
        for (int r = rg * 16; r < rg * 16 + 16; ++r)
            a += fast_exp2(bms[n2][r]) * rowinv[r];
        partial[rg][n2] = a;
    }
    __syncthreads();

    if (t < 128) {
        int n1l = t >> 6, n2 = t & 63;
        float val = (partial[2 * n1l][n2] + partial[2 * n1l + 1][n2]) * (1.0f / 512.0f);
        int n1 = qt * 2 + n1l;
        atomicAdd(&out[(b * 64 + n1) * 64 + n2], val);
    }
}

extern "C" void kernel_launch(void* const* d_in, const int* in_sizes, int n_in,
                              void* d_out, int out_size, void* d_ws, size_t ws_size,
                              hipStream_t stream) {
    const float* f1  = (const float*)d_in[0];
    const float* f2  = (const float*)d_in[1];
    const float* Wq1 = (const float*)d_in[2];
    const float* Wk1 = (const float*)d_in[3];
    const float* Wq2 = (const float*)d_in[4];
    const float* Wk2 = (const float*)d_in[5];
    const float* tau = (const float*)d_in[6];
    float* out = (float*)d_out;
    short* ws = (short*)d_ws;

    hipMemsetAsync(d_out, 0, (size_t)out_size * sizeof(float), stream);
    convert_kernel<<<dim3(2560), dim3(256), 0, stream>>>(f1, f2, Wq1, Wk1, Wq2, Wk2, tau, ws);
    proj_kernel<<<dim3(2048), dim3(256), 0, stream>>>(ws);
    attn_kernel<<<dim3(1024), dim3(256), 0, stream>>>(ws, out);
}